// Round 1
// baseline (569.854 us; speedup 1.0000x reference)
//
#include <hip/hip_runtime.h>
#include <hip/hip_bf16.h>
#include <math.h>

#define T_LEN 4096
#define BATCH 16

// ---------------------------------------------------------------------------
// Kernel 1: adapter + per-node GCN projection + A_HAT propagation + relu +
// node-mean pool.  Output h_pool stored channel-major [B][64][T] so the conv
// kernels get coalesced, LDS-friendly tiles.
//
// A_HAT structure (21 nodes: palm 0, five fingers of 4 nodes each):
//   prop[0]    = (1/6) h0 + (1/sqrt18) * sum_f h[4f+1]
//   prop[4f+1] = (1/sqrt18) h0 + (1/3)(h[4f+1]+h[4f+2])
//   prop[4f+2] = (1/3)(h[4f+1]+h[4f+2]+h[4f+3])
//   prop[4f+3] = (1/3)(h[4f+2]+h[4f+3]) + (1/sqrt6) h[4f+4]
//   prop[4f+4] = (1/sqrt6) h[4f+3] + (1/2) h[4f+4]
// ---------------------------------------------------------------------------
__global__ __launch_bounds__(256) void k_gcn_pool(
    const float* __restrict__ x,      // [B][T][218]
    const float* __restrict__ gcn_w,  // [18][64]
    float* __restrict__ hp)           // [B][64][T]
{
    __shared__ float xs[64 * 224];    // 64 timesteps x 218 (padded to 224)
    __shared__ float os[64 * 65];     // [d][t] transpose staging (pad 65)

    const int b  = blockIdx.y;
    const int t0 = blockIdx.x * 64;
    const int tid = threadIdx.x;

    // cooperative, coalesced load of 64 timesteps of x
    const float* xb = x + ((long)b * T_LEN + t0) * 218;
    for (int i = tid; i < 64 * 218; i += 256) {
        int tt = i / 218;
        int c  = i - tt * 218;
        xs[tt * 224 + c] = xb[i];
    }
    __syncthreads();

    const int lane = tid & 63;
    const int w    = tid >> 6;

    // this lane's gcn_w column (coalesced)
    float gw[18];
    #pragma unroll
    for (int c = 0; c < 18; ++c) gw[c] = gcn_w[c * 64 + lane];

    const float cP  = 1.0f / 6.0f;              // palm self
    const float cS  = 0.23570226039551584f;     // 1/sqrt(18) star edges
    const float c3  = 1.0f / 3.0f;
    const float cT  = 0.4082482904638631f;      // 1/sqrt(6) tip edge
    const float cH  = 0.5f;                     // tip self

    #pragma unroll 1
    for (int s = 0; s < 16; ++s) {
        const int tt = w * 16 + s;
        const float* xv = &xs[tt * 224];

        // node projections
        float h0 = 0.f;
        #pragma unroll
        for (int c = 0; c < 18; ++c) h0 = fmaf(xv[c], gw[c], h0);

        float hb[20];
        #pragma unroll
        for (int v = 0; v < 20; ++v) {
            const float* xp = xv + 18 + 10 * v;
            float hv = 0.f;
            #pragma unroll
            for (int c = 0; c < 10; ++c) hv = fmaf(xp[c], gw[c], hv);
            hb[v] = hv;
        }

        // sparse propagation + relu + pool
        float pool = 0.f;
        float star = 0.f;
        #pragma unroll
        for (int f = 0; f < 5; ++f) {
            const float ha = hb[4*f+0], h2 = hb[4*f+1], h3 = hb[4*f+2], he = hb[4*f+3];
            star += ha;
            const float pa = fmaf(cS, h0, c3 * (ha + h2));
            const float pb = c3 * (ha + h2 + h3);
            const float pc = fmaf(cT, he, c3 * (h2 + h3));
            const float pe = fmaf(cT, h3, cH * he);
            pool += fmaxf(pa, 0.f) + fmaxf(pb, 0.f) + fmaxf(pc, 0.f) + fmaxf(pe, 0.f);
        }
        const float p0 = fmaf(cP, h0, cS * star);
        pool += fmaxf(p0, 0.f);

        os[lane * 65 + tt] = pool * (1.0f / 21.0f);
    }
    __syncthreads();

    // coalesced channel-major store
    float* hpb = hp + (long)b * 64 * T_LEN + t0;
    for (int i = tid; i < 64 * 64; i += 256) {
        int d  = i >> 6;
        int tt = i & 63;
        hpb[(long)d * T_LEN + tt] = os[d * 65 + tt];
    }
}

// ---------------------------------------------------------------------------
// MSTCN block: three causal dilated convs (k3/d1 ->16, k5/d2 ->16, k9/d4 ->32)
// + relu, concat, 1x1 conv_out (64->64, no relu).
// One thread per timestep; input tiled in LDS as [ch][t] (stride 289).
// FINAL=true fuses the model head: dense 64->32, tanh, mean over T
// (shuffle-reduce + atomicAdd into d_out).
// ---------------------------------------------------------------------------
template <bool FINAL>
__global__ __launch_bounds__(256) void k_mstcn(
    const float* __restrict__ in,   // [B][64][T]
    const float* __restrict__ ws, const float* __restrict__ bs,
    const float* __restrict__ wm, const float* __restrict__ bm,
    const float* __restrict__ wl, const float* __restrict__ bl,
    const float* __restrict__ wo, const float* __restrict__ bo,
    float* __restrict__ out,        // [B][64][T]   (FINAL=false)
    const float* __restrict__ wd,   // [64][32]     (FINAL=true)
    const float* __restrict__ bd,   // [32]
    float* __restrict__ outp)       // [B][32]      (FINAL=true)
{
    __shared__ float tile[64 * 289]; // [ch][32 halo + 256 + pad]

    const int b  = blockIdx.y;
    const int t0 = blockIdx.x * 256;
    const int tid = threadIdx.x;

    const float* inb = in + (long)b * 64 * T_LEN;
    for (int i = tid; i < 64 * 288; i += 256) {
        int c  = i / 288;
        int tt = i - c * 288;
        int t  = t0 - 32 + tt;
        tile[c * 289 + tt] = (t >= 0) ? inb[(long)c * T_LEN + t] : 0.f;
    }
    __syncthreads();

    const int tl = tid + 32;   // this thread's timestep in tile coords

    float a1[16], a2[16], a3[32];
    #pragma unroll
    for (int j = 0; j < 16; ++j) a1[j] = bs[j];
    #pragma unroll
    for (int j = 0; j < 16; ++j) a2[j] = bm[j];
    #pragma unroll
    for (int j = 0; j < 32; ++j) a3[j] = bl[j];

    #pragma unroll 1
    for (int c = 0; c < 64; ++c) {
        const float* tr = &tile[c * 289 + tl];
        const float v0   = tr[0],   vm1  = tr[-1],  vm2  = tr[-2],  vm4  = tr[-4];
        const float vm6  = tr[-6],  vm8  = tr[-8],  vm12 = tr[-12], vm16 = tr[-16];
        const float vm20 = tr[-20], vm24 = tr[-24], vm28 = tr[-28], vm32 = tr[-32];

        // conv_s: k=3, d=1, taps t-2,t-1,t
        const float* wsc = ws + c * 16;   // [k][c][j], k-stride 1024
        {
            const float tv[3] = { vm2, vm1, v0 };
            #pragma unroll
            for (int k = 0; k < 3; ++k)
                #pragma unroll
                for (int j = 0; j < 16; ++j)
                    a1[j] = fmaf(wsc[k * 1024 + j], tv[k], a1[j]);
        }
        // conv_m: k=5, d=2, taps t-8..t step 2
        const float* wmc = wm + c * 16;
        {
            const float tv[5] = { vm8, vm6, vm4, vm2, v0 };
            #pragma unroll
            for (int k = 0; k < 5; ++k)
                #pragma unroll
                for (int j = 0; j < 16; ++j)
                    a2[j] = fmaf(wmc[k * 1024 + j], tv[k], a2[j]);
        }
        // conv_l: k=9, d=4, taps t-32..t step 4
        const float* wlc = wl + c * 32;   // k-stride 2048
        {
            const float tv[9] = { vm32, vm28, vm24, vm20, vm16, vm12, vm8, vm4, v0 };
            #pragma unroll
            for (int k = 0; k < 9; ++k)
                #pragma unroll
                for (int j = 0; j < 32; ++j)
                    a3[j] = fmaf(wlc[k * 2048 + j], tv[k], a3[j]);
        }
    }

    #pragma unroll
    for (int j = 0; j < 16; ++j) a1[j] = fmaxf(a1[j], 0.f);
    #pragma unroll
    for (int j = 0; j < 16; ++j) a2[j] = fmaxf(a2[j], 0.f);
    #pragma unroll
    for (int j = 0; j < 32; ++j) a3[j] = fmaxf(a3[j], 0.f);

    // conv_out: 64 -> 64, no relu
    float o[64];
    #pragma unroll
    for (int d = 0; d < 64; ++d) o[d] = bo[d];
    #pragma unroll 4
    for (int j = 0; j < 16; ++j) {
        const float hv = a1[j];
        const float* wr = wo + j * 64;
        #pragma unroll
        for (int d = 0; d < 64; ++d) o[d] = fmaf(wr[d], hv, o[d]);
    }
    #pragma unroll 4
    for (int j = 0; j < 16; ++j) {
        const float hv = a2[j];
        const float* wr = wo + (16 + j) * 64;
        #pragma unroll
        for (int d = 0; d < 64; ++d) o[d] = fmaf(wr[d], hv, o[d]);
    }
    #pragma unroll 4
    for (int j = 0; j < 32; ++j) {
        const float hv = a3[j];
        const float* wr = wo + (32 + j) * 64;
        #pragma unroll
        for (int d = 0; d < 64; ++d) o[d] = fmaf(wr[d], hv, o[d]);
    }

    if (!FINAL) {
        const int t = t0 + tid;
        float* ob = out + (long)b * 64 * T_LEN + t;
        #pragma unroll
        for (int d = 0; d < 64; ++d) ob[(long)d * T_LEN] = o[d];
    } else {
        // dense 64->32 + tanh + (1/T) mean, reduced across the wave
        float f[32];
        #pragma unroll
        for (int e = 0; e < 32; ++e) f[e] = bd[e];
        #pragma unroll 4
        for (int d = 0; d < 64; ++d) {
            const float v = o[d];
            const float* wr = wd + d * 32;
            #pragma unroll
            for (int e = 0; e < 32; ++e) f[e] = fmaf(wr[e], v, f[e]);
        }
        const int lane = tid & 63;
        #pragma unroll 1
        for (int e = 0; e < 32; ++e) {
            float v = tanhf(f[e]) * (1.0f / (float)T_LEN);
            v += __shfl_down(v, 32);
            v += __shfl_down(v, 16);
            v += __shfl_down(v, 8);
            v += __shfl_down(v, 4);
            v += __shfl_down(v, 2);
            v += __shfl_down(v, 1);
            if (lane == 0) atomicAdd(&outp[b * 32 + e], v);
        }
    }
}

extern "C" void kernel_launch(void* const* d_in, const int* in_sizes, int n_in,
                              void* d_out, int out_size, void* d_ws, size_t ws_size,
                              hipStream_t stream) {
    const float* x     = (const float*)d_in[0];
    const float* gcn_w = (const float*)d_in[1];
    const float* wd    = (const float*)d_in[2];
    const float* bd    = (const float*)d_in[3];
    const float* t1_ws = (const float*)d_in[4];
    const float* t1_bs = (const float*)d_in[5];
    const float* t1_wm = (const float*)d_in[6];
    const float* t1_bm = (const float*)d_in[7];
    const float* t1_wl = (const float*)d_in[8];
    const float* t1_bl = (const float*)d_in[9];
    const float* t1_wo = (const float*)d_in[10];
    const float* t1_bo = (const float*)d_in[11];
    const float* t2_ws = (const float*)d_in[12];
    const float* t2_bs = (const float*)d_in[13];
    const float* t2_wm = (const float*)d_in[14];
    const float* t2_bm = (const float*)d_in[15];
    const float* t2_wl = (const float*)d_in[16];
    const float* t2_bl = (const float*)d_in[17];
    const float* t2_wo = (const float*)d_in[18];
    const float* t2_bo = (const float*)d_in[19];

    float* hp = (float*)d_ws;                          // [16][64][4096]
    float* t1 = hp + (size_t)BATCH * 64 * T_LEN;       // [16][64][4096]

    hipMemsetAsync(d_out, 0, (size_t)out_size * sizeof(float), stream);

    k_gcn_pool<<<dim3(T_LEN / 64, BATCH), 256, 0, stream>>>(x, gcn_w, hp);

    k_mstcn<false><<<dim3(T_LEN / 256, BATCH), 256, 0, stream>>>(
        hp, t1_ws, t1_bs, t1_wm, t1_bm, t1_wl, t1_bl, t1_wo, t1_bo,
        t1, nullptr, nullptr, nullptr);

    k_mstcn<true><<<dim3(T_LEN / 256, BATCH), 256, 0, stream>>>(
        t1, t2_ws, t2_bs, t2_wm, t2_bm, t2_wl, t2_bl, t2_wo, t2_bo,
        nullptr, wd, bd, (float*)d_out);
}

// Round 2
// 373.142 us; speedup vs baseline: 1.5272x; 1.5272x over previous
//
#include <hip/hip_runtime.h>
#include <hip/hip_bf16.h>
#include <math.h>

#define T_LEN 4096
#define BATCH 16

// ---------------------------------------------------------------------------
// Kernel 1: adapter + per-node GCN projection + A_HAT propagation + relu +
// node-mean pool.  Output h_pool stored channel-major [B][64][T].
// ---------------------------------------------------------------------------
__global__ __launch_bounds__(256) void k_gcn_pool(
    const float* __restrict__ x,      // [B][T][218]
    const float* __restrict__ gcn_w,  // [18][64]
    float* __restrict__ hp)           // [B][64][T]
{
    __shared__ float xs[64 * 224];
    __shared__ float os[64 * 65];

    const int b  = blockIdx.y;
    const int t0 = blockIdx.x * 64;
    const int tid = threadIdx.x;

    const float* xb = x + ((long)b * T_LEN + t0) * 218;
    for (int i = tid; i < 64 * 218; i += 256) {
        int tt = i / 218;
        int c  = i - tt * 218;
        xs[tt * 224 + c] = xb[i];
    }
    __syncthreads();

    const int lane = tid & 63;
    const int w    = tid >> 6;

    float gw[18];
    #pragma unroll
    for (int c = 0; c < 18; ++c) gw[c] = gcn_w[c * 64 + lane];

    const float cP  = 1.0f / 6.0f;
    const float cS  = 0.23570226039551584f;     // 1/sqrt(18)
    const float c3  = 1.0f / 3.0f;
    const float cT  = 0.4082482904638631f;      // 1/sqrt(6)
    const float cH  = 0.5f;

    #pragma unroll 1
    for (int s = 0; s < 16; ++s) {
        const int tt = w * 16 + s;
        const float* xv = &xs[tt * 224];

        float h0 = 0.f;
        #pragma unroll
        for (int c = 0; c < 18; ++c) h0 = fmaf(xv[c], gw[c], h0);

        float hb[20];
        #pragma unroll
        for (int v = 0; v < 20; ++v) {
            const float* xp = xv + 18 + 10 * v;
            float hv = 0.f;
            #pragma unroll
            for (int c = 0; c < 10; ++c) hv = fmaf(xp[c], gw[c], hv);
            hb[v] = hv;
        }

        float pool = 0.f;
        float star = 0.f;
        #pragma unroll
        for (int f = 0; f < 5; ++f) {
            const float ha = hb[4*f+0], h2 = hb[4*f+1], h3 = hb[4*f+2], he = hb[4*f+3];
            star += ha;
            const float pa = fmaf(cS, h0, c3 * (ha + h2));
            const float pb = c3 * (ha + h2 + h3);
            const float pc = fmaf(cT, he, c3 * (h2 + h3));
            const float pe = fmaf(cT, h3, cH * he);
            pool += fmaxf(pa, 0.f) + fmaxf(pb, 0.f) + fmaxf(pc, 0.f) + fmaxf(pe, 0.f);
        }
        const float p0 = fmaf(cP, h0, cS * star);
        pool += fmaxf(p0, 0.f);

        os[lane * 65 + tt] = pool * (1.0f / 21.0f);
    }
    __syncthreads();

    float* hpb = hp + (long)b * 64 * T_LEN + t0;
    for (int i = tid; i < 64 * 64; i += 256) {
        int d  = i >> 6;
        int tt = i & 63;
        hpb[(long)d * T_LEN + tt] = os[d * 65 + tt];
    }
}

// ---------------------------------------------------------------------------
// MSTCN block, register-blocked:
//   block = 256 threads = 16 j-groups x 16 t-threads; t-tile = 64, all 64 j.
//   thread computes 4 j x 4 t (16 accumulators); each weight float4 feeds
//   16 FMAs.  Conv type is wave-uniform (wave0=conv_s, wave1=conv_m,
//   waves2-3=conv_l): no divergence.
//   LDS: input tile [64c][96+pad] (25.6 KB), aliased for h[64j][64t+pad]
//   staging before the 1x1 conv_out, and (FINAL) for the fused head.
// ---------------------------------------------------------------------------
template <bool FINAL>
__global__ __launch_bounds__(256) void k_mstcn(
    const float* __restrict__ in,   // [B][64][T]
    const float* __restrict__ ws, const float* __restrict__ bs,
    const float* __restrict__ wm, const float* __restrict__ bm,
    const float* __restrict__ wl, const float* __restrict__ bl,
    const float* __restrict__ wo, const float* __restrict__ bo,
    float* __restrict__ out,        // [B][64][T]   (FINAL=false)
    const float* __restrict__ wd,   // [64][32]     (FINAL=true)
    const float* __restrict__ bd,   // [32]
    float* __restrict__ outp)       // [B][32]      (FINAL=true)
{
    __shared__ float smem[64 * 100];   // tile [c][96] stride 100; aliased later

    const int b   = blockIdx.y;
    const int t0  = blockIdx.x * 64;
    const int tid = threadIdx.x;
    const int jg  = tid >> 4;          // 0..15  (j-group of 4)
    const int tt  = tid & 15;          // 0..15  (t-group of 4)
    const int j0g = jg * 4;            // global concat channel base

    // ---- stage input window [t0-32, t0+63] as [c][96], row stride 100 ----
    const float* inb = in + (long)b * 64 * T_LEN;
    #pragma unroll 1
    for (int i = tid; i < 64 * 24; i += 256) {
        const int c = i / 24;
        const int q = i - c * 24;
        const int t = t0 - 32 + q * 4;
        float4 v = make_float4(0.f, 0.f, 0.f, 0.f);
        if (t >= 0) v = *(const float4*)(inb + (long)c * T_LEN + t);
        *(float4*)(&smem[c * 100 + q * 4]) = v;
    }
    __syncthreads();

    float acc[4][4];

    if (jg < 4) {
        // conv_s: k=3, d=1  (concat j 0..15)
        #pragma unroll
        for (int ji = 0; ji < 4; ++ji) {
            const float bv = bs[j0g + ji];
            #pragma unroll
            for (int ti = 0; ti < 4; ++ti) acc[ji][ti] = bv;
        }
        #pragma unroll 1
        for (int c = 0; c < 64; ++c) {
            const float4* rowq = (const float4*)(&smem[c * 100]);
            float win[8];                       // window pos wb-4 .. wb+3
            *(float4*)(&win[0]) = rowq[tt + 7];
            *(float4*)(&win[4]) = rowq[tt + 8];
            #pragma unroll
            for (int k = 0; k < 3; ++k) {
                const int off = 2 - k;
                float wv[4];
                *(float4*)wv = *(const float4*)(ws + (k * 64 + c) * 16 + j0g);
                #pragma unroll
                for (int ti = 0; ti < 4; ++ti) {
                    const float v = win[4 + ti - off];
                    #pragma unroll
                    for (int ji = 0; ji < 4; ++ji)
                        acc[ji][ti] = fmaf(wv[ji], v, acc[ji][ti]);
                }
            }
        }
    } else if (jg < 8) {
        // conv_m: k=5, d=2  (concat j 16..31)
        #pragma unroll
        for (int ji = 0; ji < 4; ++ji) {
            const float bv = bm[j0g - 16 + ji];
            #pragma unroll
            for (int ti = 0; ti < 4; ++ti) acc[ji][ti] = bv;
        }
        #pragma unroll 1
        for (int c = 0; c < 64; ++c) {
            const float4* rowq = (const float4*)(&smem[c * 100]);
            float win[12];                      // window pos wb-8 .. wb+3
            *(float4*)(&win[0]) = rowq[tt + 6];
            *(float4*)(&win[4]) = rowq[tt + 7];
            *(float4*)(&win[8]) = rowq[tt + 8];
            #pragma unroll
            for (int k = 0; k < 5; ++k) {
                const int off = (4 - k) * 2;
                float wv[4];
                *(float4*)wv = *(const float4*)(wm + (k * 64 + c) * 16 + (j0g - 16));
                #pragma unroll
                for (int ti = 0; ti < 4; ++ti) {
                    const float v = win[8 + ti - off];
                    #pragma unroll
                    for (int ji = 0; ji < 4; ++ji)
                        acc[ji][ti] = fmaf(wv[ji], v, acc[ji][ti]);
                }
            }
        }
    } else {
        // conv_l: k=9, d=4  (concat j 32..63)
        #pragma unroll
        for (int ji = 0; ji < 4; ++ji) {
            const float bv = bl[j0g - 32 + ji];
            #pragma unroll
            for (int ti = 0; ti < 4; ++ti) acc[ji][ti] = bv;
        }
        #pragma unroll 1
        for (int c = 0; c < 64; ++c) {
            const float4* rowq = (const float4*)(&smem[c * 100]);
            float win[36];                      // window pos wb-32 .. wb+3
            #pragma unroll
            for (int m = 0; m < 9; ++m)
                *(float4*)(&win[4 * m]) = rowq[tt + m];
            #pragma unroll
            for (int k = 0; k < 9; ++k) {
                float wv[4];
                *(float4*)wv = *(const float4*)(wl + (k * 64 + c) * 32 + (j0g - 32));
                #pragma unroll
                for (int ti = 0; ti < 4; ++ti) {
                    const float v = win[4 * k + ti];   // 32+ti-(8-k)*4
                    #pragma unroll
                    for (int ji = 0; ji < 4; ++ji)
                        acc[ji][ti] = fmaf(wv[ji], v, acc[ji][ti]);
                }
            }
        }
    }

    // relu
    #pragma unroll
    for (int ji = 0; ji < 4; ++ji)
        #pragma unroll
        for (int ti = 0; ti < 4; ++ti) acc[ji][ti] = fmaxf(acc[ji][ti], 0.f);

    // ---- stage h [j][64t] (stride 68), aliasing the input tile ----
    __syncthreads();
    #pragma unroll
    for (int ji = 0; ji < 4; ++ji)
        *(float4*)(&smem[(j0g + ji) * 68 + tt * 4]) =
            make_float4(acc[ji][0], acc[ji][1], acc[ji][2], acc[ji][3]);
    __syncthreads();

    // ---- conv_out 64->64 (no relu): thread = 4 d x 4 t ----
    float o[4][4];
    {
        float bv[4];
        *(float4*)bv = *(const float4*)(bo + j0g);
        #pragma unroll
        for (int di = 0; di < 4; ++di)
            #pragma unroll
            for (int ti = 0; ti < 4; ++ti) o[di][ti] = bv[di];
    }
    #pragma unroll 1
    for (int j = 0; j < 64; ++j) {
        float hv[4], wv[4];
        *(float4*)hv = *(const float4*)(&smem[j * 68 + tt * 4]);
        *(float4*)wv = *(const float4*)(wo + j * 64 + j0g);
        #pragma unroll
        for (int di = 0; di < 4; ++di)
            #pragma unroll
            for (int ti = 0; ti < 4; ++ti)
                o[di][ti] = fmaf(wv[di], hv[ti], o[di][ti]);
    }

    if (!FINAL) {
        float* ob = out + (long)b * 64 * T_LEN + t0 + tt * 4;
        #pragma unroll
        for (int di = 0; di < 4; ++di)
            *(float4*)(ob + (long)(j0g + di) * T_LEN) =
                make_float4(o[di][0], o[di][1], o[di][2], o[di][3]);
    } else {
        // ---- fused head: dense 64->32 + tanh + mean over T ----
        __syncthreads();
        #pragma unroll
        for (int di = 0; di < 4; ++di)
            *(float4*)(&smem[(j0g + di) * 68 + tt * 4]) =
                make_float4(o[di][0], o[di][1], o[di][2], o[di][3]);
        __syncthreads();

        const int tl = tid & 63;       // local timestep
        const int eg = tid >> 6;       // wave -> 8 output features
        const int e0 = eg * 8;
        float f[8];
        *(float4*)(&f[0]) = *(const float4*)(bd + e0);
        *(float4*)(&f[4]) = *(const float4*)(bd + e0 + 4);
        #pragma unroll 1
        for (int d = 0; d < 64; ++d) {
            const float v = smem[d * 68 + tl];
            float wa[4], wb4[4];
            *(float4*)wa  = *(const float4*)(wd + d * 32 + e0);
            *(float4*)wb4 = *(const float4*)(wd + d * 32 + e0 + 4);
            #pragma unroll
            for (int e = 0; e < 4; ++e) f[e]     = fmaf(wa[e],  v, f[e]);
            #pragma unroll
            for (int e = 0; e < 4; ++e) f[4 + e] = fmaf(wb4[e], v, f[4 + e]);
        }
        #pragma unroll
        for (int e = 0; e < 8; ++e) {
            float v = tanhf(f[e]) * (1.0f / (float)T_LEN);
            v += __shfl_down(v, 32);
            v += __shfl_down(v, 16);
            v += __shfl_down(v, 8);
            v += __shfl_down(v, 4);
            v += __shfl_down(v, 2);
            v += __shfl_down(v, 1);
            if (tl == 0) atomicAdd(&outp[b * 32 + e0 + e], v);
        }
    }
}

extern "C" void kernel_launch(void* const* d_in, const int* in_sizes, int n_in,
                              void* d_out, int out_size, void* d_ws, size_t ws_size,
                              hipStream_t stream) {
    const float* x     = (const float*)d_in[0];
    const float* gcn_w = (const float*)d_in[1];
    const float* wd    = (const float*)d_in[2];
    const float* bd    = (const float*)d_in[3];
    const float* t1_ws = (const float*)d_in[4];
    const float* t1_bs = (const float*)d_in[5];
    const float* t1_wm = (const float*)d_in[6];
    const float* t1_bm = (const float*)d_in[7];
    const float* t1_wl = (const float*)d_in[8];
    const float* t1_bl = (const float*)d_in[9];
    const float* t1_wo = (const float*)d_in[10];
    const float* t1_bo = (const float*)d_in[11];
    const float* t2_ws = (const float*)d_in[12];
    const float* t2_bs = (const float*)d_in[13];
    const float* t2_wm = (const float*)d_in[14];
    const float* t2_bm = (const float*)d_in[15];
    const float* t2_wl = (const float*)d_in[16];
    const float* t2_bl = (const float*)d_in[17];
    const float* t2_wo = (const float*)d_in[18];
    const float* t2_bo = (const float*)d_in[19];

    float* hp = (float*)d_ws;                          // [16][64][4096]
    float* t1 = hp + (size_t)BATCH * 64 * T_LEN;       // [16][64][4096]

    hipMemsetAsync(d_out, 0, (size_t)out_size * sizeof(float), stream);

    k_gcn_pool<<<dim3(T_LEN / 64, BATCH), 256, 0, stream>>>(x, gcn_w, hp);

    k_mstcn<false><<<dim3(T_LEN / 64, BATCH), 256, 0, stream>>>(
        hp, t1_ws, t1_bs, t1_wm, t1_bm, t1_wl, t1_bl, t1_wo, t1_bo,
        t1, nullptr, nullptr, nullptr);

    k_mstcn<true><<<dim3(T_LEN / 64, BATCH), 256, 0, stream>>>(
        t1, t2_ws, t2_bs, t2_wm, t2_bm, t2_wl, t2_bl, t2_wo, t2_bo,
        nullptr, wd, bd, (float*)d_out);
}